// Round 9
// baseline (665.895 us; speedup 1.0000x reference)
//
#include <hip/hip_runtime.h>
#include <hip/hip_fp16.h>
#include <math.h>

#define N_NODES 50000
#define N_PAD   50176            // 392*128, padded rows for unguarded GEMM A-tiles
#define N_EDGES 800000
#define ET (N_EDGES + N_NODES)   // 850000 with self loops
#define IN_CH 128
#define H 256
#define G_GRAPHS 128
#define NEG_SLOPE 0.2f
#define NB 391                   // node buckets of 128: ceil(50000/128)

typedef __attribute__((ext_vector_type(8))) short short8;
typedef __attribute__((ext_vector_type(4))) float f32x4;
typedef __attribute__((ext_vector_type(2))) float f32x2;
typedef unsigned short u16;
typedef unsigned char u8;

#if __has_builtin(__builtin_amdgcn_cvt_f32_fp8) && __has_builtin(__builtin_amdgcn_cvt_pk_fp8_f32)
#define USE_FP8_BUILTINS 1
#else
#define USE_FP8_BUILTINS 0
#endif
#if USE_FP8_BUILTINS && __has_builtin(__builtin_amdgcn_cvt_pk_f32_fp8)
#define HAVE_PK_DEC 1
#else
#define HAVE_PK_DEC 0
#endif

__device__ inline u16 f2bf(float v) {
    unsigned u = __float_as_uint(v);
    unsigned r = (u + 0x7FFFu + ((u >> 16) & 1u)) >> 16;
    return (u16)r;
}
__device__ inline float bf2f(u16 v) {
    return __uint_as_float(((unsigned)v) << 16);
}

// ---- fp8 e4m3fn helpers -------------------------------------------------
#if USE_FP8_BUILTINS
#define FP8_WSCALE 1.0f
__device__ inline unsigned fp8_pack4(float a, float b, float c, float d) {
    int v = 0;
    v = __builtin_amdgcn_cvt_pk_fp8_f32(a, b, v, false);
    v = __builtin_amdgcn_cvt_pk_fp8_f32(c, d, v, true);
    return (unsigned)v;
}
__device__ inline void fp8_dec4(unsigned rv, float& f0, float& f1, float& f2, float& f3) {
#if HAVE_PK_DEC
    f32x2 lo = __builtin_amdgcn_cvt_pk_f32_fp8((int)rv, false);
    f32x2 hi = __builtin_amdgcn_cvt_pk_f32_fp8((int)rv, true);
    f0 = lo.x; f1 = lo.y; f2 = hi.x; f3 = hi.y;
#else
    f0 = __builtin_amdgcn_cvt_f32_fp8((int)rv, 0);
    f1 = __builtin_amdgcn_cvt_f32_fp8((int)rv, 1);
    f2 = __builtin_amdgcn_cvt_f32_fp8((int)rv, 2);
    f3 = __builtin_amdgcn_cvt_f32_fp8((int)rv, 3);
#endif
}
#else
#define FP8_WSCALE 256.0f
__device__ inline u8 fp8_enc1(float f) {
    unsigned u = __float_as_uint(f);
    unsigned s = (u >> 31) << 7;
    float a = fabsf(f);
    if (a >= 448.f) return (u8)(s | 0x7E);
    unsigned bits = __float_as_uint(a);
    int exp = (int)((bits >> 23) & 255) - 127;
    unsigned m23 = bits & 0x7fffff;
    if (exp < -6) {
        int m = (int)rintf(a * 512.f);
        if (m >= 8) return (u8)(s | (1 << 3));
        return (u8)(s | m);
    }
    int e8 = exp + 7;
    unsigned m = m23 >> 20, rem = m23 & 0xFFFFF;
    if (rem > 0x80000 || (rem == 0x80000 && (m & 1))) m++;
    if (m == 8) { m = 0; e8++; }
    if (e8 > 15 || (e8 == 15 && m == 7)) return (u8)(s | 0x7E);
    return (u8)(s | (e8 << 3) | m);
}
__device__ inline unsigned fp8_pack4(float a, float b, float c, float d) {
    return (unsigned)fp8_enc1(a) | ((unsigned)fp8_enc1(b) << 8) |
           ((unsigned)fp8_enc1(c) << 16) | ((unsigned)fp8_enc1(d) << 24);
}
// half-trick decode: e4m3 bits in f16 give value * 2^-8 (fold 256 into weights)
__device__ inline void fp8_dec4(unsigned rv, float& f0, float& f1, float& f2, float& f3) {
    unsigned hA = ((rv & 0x00800080u) << 8) | ((rv & 0x007f007fu) << 7);
    unsigned rs = rv >> 8;
    unsigned hB = ((rs & 0x00800080u) << 8) | ((rs & 0x007f007fu) << 7);
    __half2 a = *(__half2*)&hA;
    __half2 b = *(__half2*)&hB;
    f0 = __low2float(a);  f2 = __high2float(a);
    f1 = __low2float(b);  f3 = __high2float(b);
}
#endif

// async global->LDS 16B copy (dest must be wave-uniform base + lane*16)
__device__ inline void async_cp16(const u16* g, u16* l) {
    __builtin_amdgcn_global_load_lds(
        (const __attribute__((address_space(1))) unsigned int*)g,
        (__attribute__((address_space(3))) unsigned int*)l,
        16, 0, 0);
}

// =========================== CSR build (bucketed) ========================
__global__ __launch_bounds__(256) void bucket_hist(const int* __restrict__ ei,
                                                   int* __restrict__ gcnt) {
    __shared__ int h[NB];
    int t = threadIdx.x;
    for (int b = t; b < NB; b += 256) h[b] = 0;
    __syncthreads();
    for (int e = blockIdx.x * 256 + t; e < N_EDGES; e += gridDim.x * 256)
        atomicAdd(&h[ei[N_EDGES + e] >> 7], 1);
    __syncthreads();
    for (int b = t; b < NB; b += 256)
        if (h[b]) atomicAdd(&gcnt[b], h[b]);
}

__global__ __launch_bounds__(512) void bucket_scan(const int* __restrict__ gcnt,
                                                   int* __restrict__ off,
                                                   int* __restrict__ cur) {
    __shared__ int s[NB + 1];
    int t = threadIdx.x;
    if (t < NB) s[t] = gcnt[t];
    __syncthreads();
    if (t == 0) {
        int a = 0;
        for (int b = 0; b < NB; b++) { int c = s[b]; s[b] = a; a += c; }
        s[NB] = a;
    }
    __syncthreads();
    if (t <= NB) { off[t] = s[t]; if (t < NB) cur[t] = s[t]; }
}

#define EPT 16
__global__ __launch_bounds__(256) void bucket_scatter(const int* __restrict__ ei,
                                                      int* __restrict__ bucketCur,
                                                      int2* __restrict__ rec) {
    __shared__ int cnt[NB];
    __shared__ int base[NB];
    int t = threadIdx.x;
    for (int b = t; b < NB; b += 256) cnt[b] = 0;
    __syncthreads();
    int e0 = blockIdx.x * (256 * EPT);
    int sa[EPT], da[EPT], rk[EPT];
#pragma unroll
    for (int k = 0; k < EPT; k++) {
        int e = e0 + k * 256 + t;
        if (e < N_EDGES) {
            sa[k] = ei[e];
            da[k] = ei[N_EDGES + e];
            rk[k] = atomicAdd(&cnt[da[k] >> 7], 1);
        }
    }
    __syncthreads();
    for (int b = t; b < NB; b += 256) {
        int c = cnt[b];
        base[b] = c ? atomicAdd(&bucketCur[b], c) : 0;
    }
    __syncthreads();
#pragma unroll
    for (int k = 0; k < EPT; k++) {
        int e = e0 + k * 256 + t;
        if (e < N_EDGES) rec[base[da[k] >> 7] + rk[k]] = make_int2(sa[k], da[k]);
    }
}

// one block per bucket: node histogram + local scan + indptr + CSR scatter
__global__ __launch_bounds__(256) void build_csr(const int2* __restrict__ rec,
                                                 const int* __restrict__ off,
                                                 int* __restrict__ indptr,
                                                 int* __restrict__ eidsSrc) {
    __shared__ int cnt[128];
    __shared__ int scn[128];
    __shared__ int cur[128];
    int b = blockIdx.x, t = threadIdx.x;
    int nInB = N_NODES - b * 128;
    if (nInB > 128) nInB = 128;
    if (t < 128) cnt[t] = 0;
    __syncthreads();
    int lo = off[b], hi = off[b + 1];
    for (int i = lo + t; i < hi; i += 256) atomicAdd(&cnt[rec[i].y & 127], 1);
    __syncthreads();
    if (t < 128) scn[t] = cnt[t] + 1;   // +1 self loop
    __syncthreads();
    for (int o = 1; o < 128; o <<= 1) {
        int v = 0;
        if (t < 128 && t >= o) v = scn[t - o];
        __syncthreads();
        if (t < 128 && t >= o) scn[t] += v;
        __syncthreads();
    }
    int base = off[b] + 128 * b;        // edges + self loops before this bucket
    if (t < nInB) {
        int start = base + (t ? scn[t - 1] : 0);
        int node = b * 128 + t;
        indptr[node] = start;
        eidsSrc[start] = node;          // self loop slot
        cur[t] = start + 1;
    }
    if (b == 0 && t == 0) indptr[N_NODES] = ET;
    __syncthreads();
    for (int i = lo + t; i < hi; i += 256) {
        int2 r = rec[i];
        int pos = atomicAdd(&cur[r.y & 127], 1);
        eidsSrc[pos] = r.x;
    }
}

// ------------------------------------------------- combined conversions
__global__ __launch_bounds__(256) void prep_kernel(const float* __restrict__ x,
                                                   const float* __restrict__ Wih,
                                                   const float* __restrict__ W0,
                                                   const float* __restrict__ W1,
                                                   u16* __restrict__ x_bf,
                                                   u16* __restrict__ Wih_bf,
                                                   u16* __restrict__ W0t,
                                                   u16* __restrict__ W1t) {
    int i = blockIdx.x * 256 + threadIdx.x;
    int seg = blockIdx.y;
    if (seg == 0) {
        if (i < N_NODES * IN_CH / 4) {
            float4 v = *(const float4*)&x[i * 4];
            ushort4 o = {f2bf(v.x), f2bf(v.y), f2bf(v.z), f2bf(v.w)};
            *(ushort4*)&x_bf[i * 4] = o;
        }
    } else if (seg == 1) {
        if (i < 3 * H * H / 4) {
            float4 v = *(const float4*)&Wih[i * 4];
            ushort4 o = {f2bf(v.x), f2bf(v.y), f2bf(v.z), f2bf(v.w)};
            *(ushort4*)&Wih_bf[i * 4] = o;
        }
    } else if (seg == 2) {
        if (i < IN_CH * H) {
            int k = i / H, n = i % H;
            W0t[(size_t)n * IN_CH + k] = f2bf(W0[i]);
        }
    } else {
        if (i < H * H) {
            int k = i / H, n = i % H;
            W1t[(size_t)n * H + k] = f2bf(W1[i]);
        }
    }
}

// ------------------------------------------------------------ MFMA GEMM (wide)
// C[M,Ntot] = A[M,K](bf16) @ Bt[Ntot,K]^T (bf16), fp32 acc, bf16 out.
// 128x256 tile, BK=32, 256 thr = 4 waves (2m x 2n of 64x128).
// XOR-swizzled LDS chunk placement (conflict-minimal, global_load_lds-safe).
// launch_bounds(256,4): 4 blocks/CU (VGPR<=128, LDS 4x24KB=96KB) for latency hiding.
__global__ __launch_bounds__(256, 4) void gemm_wide(const u16* __restrict__ A,
                                                    const u16* __restrict__ Bt,
                                                    u16* __restrict__ C,
                                                    int M, int K, int Ntot) {
    __shared__ u16 As[128][32];   // 8 KB, NO pad (global_load_lds contiguity)
    __shared__ u16 Bs[256][32];   // 16 KB
    int t = threadIdx.x;
    int m0 = blockIdx.x * 128;
    int n0 = blockIdx.y * 256;
    int wave = t >> 6, lane = t & 63;
    int wm = (wave >> 1) * 64, wn = (wave & 1) * 128;
    int lrow = lane & 15;
    int lq = lane >> 4;

    f32x4 acc[4][8];
#pragma unroll
    for (int i = 0; i < 4; i++)
#pragma unroll
        for (int j = 0; j < 8; j++)
            acc[i][j] = (f32x4){0.f, 0.f, 0.f, 0.f};

    // thread t stages slot (r0, t&3); swizzle -> fetch global k-quad qs
    int r0 = t >> 2;
    int qs = (t & 3) ^ ((t >> 3) & 3);   // (t&3) ^ ((r0>>1)&3)
    const u16* gA0 = A + (size_t)(m0 + r0) * K + qs * 8;
    const u16* gA1 = gA0 + (size_t)64 * K;
    const u16* gB0 = Bt + (size_t)(n0 + r0) * K + qs * 8;
    const u16* gB1 = gB0 + (size_t)64 * K;
    const u16* gB2 = gB0 + (size_t)128 * K;
    const u16* gB3 = gB0 + (size_t)192 * K;
    u16* lA0 = &As[0][0] + t * 8;
    u16* lA1 = lA0 + 256 * 8;
    u16* lB0 = &Bs[0][0] + t * 8;
    u16* lB1 = lB0 + 256 * 8;
    u16* lB2 = lB0 + 512 * 8;
    u16* lB3 = lB0 + 768 * 8;

    int swz8 = (lq ^ ((lrow >> 1) & 3)) * 8;   // reader-side swizzled column

    for (int k0 = 0; k0 < K; k0 += 32) {
        __syncthreads();
        async_cp16(gA0 + k0, lA0);
        async_cp16(gA1 + k0, lA1);
        async_cp16(gB0 + k0, lB0);
        async_cp16(gB1 + k0, lB1);
        async_cp16(gB2 + k0, lB2);
        async_cp16(gB3 + k0, lB3);
        __syncthreads();
        short8 af[4], bfr[8];
#pragma unroll
        for (int i = 0; i < 4; i++)
            af[i] = *(const short8*)&As[wm + i * 16 + lrow][swz8];
#pragma unroll
        for (int j = 0; j < 8; j++)
            bfr[j] = *(const short8*)&Bs[wn + j * 16 + lrow][swz8];
#pragma unroll
        for (int i = 0; i < 4; i++)
#pragma unroll
            for (int j = 0; j < 8; j++)
                acc[i][j] = __builtin_amdgcn_mfma_f32_16x16x32_bf16(af[i], bfr[j], acc[i][j], 0, 0, 0);
    }
    // C/D layout: col = lane&15, row = (lane>>4)*4 + reg
#pragma unroll
    for (int i = 0; i < 4; i++) {
#pragma unroll
        for (int reg = 0; reg < 4; reg++) {
            int gm = m0 + wm + i * 16 + lq * 4 + reg;
            if (gm < M) {
#pragma unroll
                for (int j = 0; j < 8; j++) {
                    int gn = n0 + wn + j * 16 + lrow;
                    C[(size_t)gm * Ntot + gn] = f2bf(acc[i][j][reg]);
                }
            }
        }
    }
}

// ------------------------------------------- attention pre-dots + fp8 encode
__global__ __launch_bounds__(256) void sdot_fp8(const u16* __restrict__ xp,
                                                const float* __restrict__ a_src,
                                                const float* __restrict__ a_dst,
                                                float* __restrict__ s_src,
                                                float* __restrict__ s_dst,
                                                u8* __restrict__ xp8) {
    int wave = threadIdx.x >> 6, lane = threadIdx.x & 63;
    int n = blockIdx.x * 4 + wave;
    int col = lane << 2;
    ushort4 v = *(const ushort4*)&xp[(size_t)n * H + col];
    float4 a1 = *(const float4*)&a_src[col];
    float4 a2 = *(const float4*)&a_dst[col];
    float x0 = bf2f(v.x), x1 = bf2f(v.y), x2 = bf2f(v.z), x3 = bf2f(v.w);
    *(unsigned*)&xp8[(size_t)n * H + col] = fp8_pack4(x0, x1, x2, x3);
    float d1 = x0 * a1.x + x1 * a1.y + x2 * a1.z + x3 * a1.w;
    float d2 = x0 * a2.x + x1 * a2.y + x2 * a2.z + x3 * a2.w;
#pragma unroll
    for (int off = 32; off; off >>= 1) {
        d1 += __shfl_xor(d1, off);
        d2 += __shfl_xor(d2, off);
    }
    if (lane == 0) { s_src[n] = d1; s_dst[n] = d2; }
}

// --------------------------------------------------------- GAT aggregation
// wave per node; CSR stores src directly; fp8 value gather; 16-deep batching
__global__ __launch_bounds__(256) void gat_agg_fp8(const u8* __restrict__ xp8,
                                                   const float* __restrict__ s_src,
                                                   const float* __restrict__ s_dst,
                                                   const int* __restrict__ indptr,
                                                   const int* __restrict__ eidsSrc,
                                                   const float* __restrict__ bias,
                                                   u16* __restrict__ out) {
    __shared__ int2 sSW[4][64];
    int wave = threadIdx.x >> 6, lane = threadIdx.x & 63;
    int n = blockIdx.x * 4 + wave;
    int start = indptr[n];
    int deg = indptr[n + 1] - start;
    float sdn = s_dst[n];
    int col = lane << 2;
    float a0 = 0.f, a1 = 0.f, a2 = 0.f, a3 = 0.f;

    if (deg <= 64) {
        int s = 0;
        float v = -1e30f;
        if (lane < deg) {
            s = eidsSrc[start + lane];
            float u = s_src[s] + sdn;
            v = (u >= 0.f) ? u : NEG_SLOPE * u;
        }
        float m = v;
#pragma unroll
        for (int off = 32; off; off >>= 1) m = fmaxf(m, __shfl_xor(m, off));
        float pw = (lane < deg) ? expf(v - m) : 0.f;
        float dsum = pw;
#pragma unroll
        for (int off = 32; off; off >>= 1) dsum += __shfl_xor(dsum, off);
        float w = pw * (FP8_WSCALE / dsum);
        sSW[wave][lane] = make_int2(s * H, __float_as_int(w));   // premul row offset
        int j = 0;
        for (; j + 16 <= deg; j += 16) {
            unsigned rv[16];
            float wv[16];
#pragma unroll
            for (int k = 0; k < 16; k++) {
                int2 sw = sSW[wave][j + k];
                wv[k] = __int_as_float(sw.y);
                rv[k] = *(const unsigned*)&xp8[(size_t)(unsigned)sw.x + col];
            }
#pragma unroll
            for (int k = 0; k < 16; k++) {
                float f0, f1, f2, f3;
                fp8_dec4(rv[k], f0, f1, f2, f3);
                a0 += wv[k] * f0; a1 += wv[k] * f1;
                a2 += wv[k] * f2; a3 += wv[k] * f3;
            }
        }
        if (j + 8 <= deg) {
            unsigned rv[8];
            float wv[8];
#pragma unroll
            for (int k = 0; k < 8; k++) {
                int2 sw = sSW[wave][j + k];
                wv[k] = __int_as_float(sw.y);
                rv[k] = *(const unsigned*)&xp8[(size_t)(unsigned)sw.x + col];
            }
#pragma unroll
            for (int k = 0; k < 8; k++) {
                float f0, f1, f2, f3;
                fp8_dec4(rv[k], f0, f1, f2, f3);
                a0 += wv[k] * f0; a1 += wv[k] * f1;
                a2 += wv[k] * f2; a3 += wv[k] * f3;
            }
            j += 8;
        }
        for (; j < deg; j++) {
            int2 sw = sSW[wave][j];
            float wj = __int_as_float(sw.y);
            unsigned rv = *(const unsigned*)&xp8[(size_t)(unsigned)sw.x + col];
            float f0, f1, f2, f3;
            fp8_dec4(rv, f0, f1, f2, f3);
            a0 += wj * f0; a1 += wj * f1; a2 += wj * f2; a3 += wj * f3;
        }
    } else {
        float m = -1e30f;
        for (int i = lane; i < deg; i += 64) {
            int s = eidsSrc[start + i];
            float u = s_src[s] + sdn;
            u = (u >= 0.f) ? u : NEG_SLOPE * u;
            m = fmaxf(m, u);
        }
#pragma unroll
        for (int off = 32; off; off >>= 1) m = fmaxf(m, __shfl_xor(m, off));
        float dsum = 0.f;
        for (int i = lane; i < deg; i += 64) {
            int s = eidsSrc[start + i];
            float u = s_src[s] + sdn;
            u = (u >= 0.f) ? u : NEG_SLOPE * u;
            dsum += expf(u - m);
        }
#pragma unroll
        for (int off = 32; off; off >>= 1) dsum += __shfl_xor(dsum, off);
        float dinv = FP8_WSCALE / dsum;
        for (int base = 0; base < deg; base += 64) {
            int cnt = min(64, deg - base);
            int s = 0; float w = 0.f;
            if (lane < cnt) {
                s = eidsSrc[start + base + lane];
                float u = s_src[s] + sdn;
                u = (u >= 0.f) ? u : NEG_SLOPE * u;
                w = expf(u - m) * dinv;
            }
            sSW[wave][lane] = make_int2(s * H, __float_as_int(w));
            for (int j = 0; j < cnt; j++) {
                int2 sw = sSW[wave][j];
                float wj = __int_as_float(sw.y);
                unsigned rv = *(const unsigned*)&xp8[(size_t)(unsigned)sw.x + col];
                float f0, f1, f2, f3;
                fp8_dec4(rv, f0, f1, f2, f3);
                a0 += wj * f0; a1 += wj * f1; a2 += wj * f2; a3 += wj * f3;
            }
        }
    }
    float4 bv = *(const float4*)&bias[col];
    ushort4 o;
    o.x = f2bf(fmaxf(a0 + bv.x, 0.f));
    o.y = f2bf(fmaxf(a1 + bv.y, 0.f));
    o.z = f2bf(fmaxf(a2 + bv.z, 0.f));
    o.w = f2bf(fmaxf(a3 + bv.w, 0.f));
    *(ushort4*)&out[(size_t)n * H + col] = o;
}

// ------------------------------------------------- GRU gates + pooling (fused)
__global__ __launch_bounds__(256) void gru_gates_pool(const u16* __restrict__ gates,
                                                      const float* __restrict__ b_ih,
                                                      const float* __restrict__ b_hh,
                                                      const int* __restrict__ batch,
                                                      float* __restrict__ pooled) {
    int t = threadIdx.x;
    int i0 = blockIdx.x * 16;
    if (i0 >= N_NODES) return;
    float bir = b_ih[t], biz = b_ih[256 + t], bin_ = b_ih[512 + t];
    float bhr = b_hh[t], bhz = b_hh[256 + t], bhn = b_hh[512 + t];
    int iend = min(16, N_NODES - i0);
    float acc = 0.f;
    int cur_g = batch[i0];
    for (int i = 0; i < iend; i++) {
        size_t row = (size_t)(i0 + i) * 768;
        float ir = bf2f(gates[row + t]);
        float iz = bf2f(gates[row + 256 + t]);
        float in_ = bf2f(gates[row + 512 + t]);
        float r = 1.f / (1.f + expf(-(ir + bir + bhr)));
        float z = 1.f / (1.f + expf(-(iz + biz + bhz)));
        float nn = tanhf(in_ + bin_ + r * bhn);
        float h = (1.f - z) * nn;
        int g = batch[i0 + i];
        if (g != cur_g) {
            atomicAdd(&pooled[(size_t)cur_g * H + t], acc);
            acc = 0.f;
            cur_g = g;
        }
        acc += h;
    }
    atomicAdd(&pooled[(size_t)cur_g * H + t], acc);
}

// --------------------------------------------------------------- super node
__global__ __launch_bounds__(256) void super_kernel(const float* __restrict__ pooled,
                                                    const float* __restrict__ Wf,
                                                    const float* __restrict__ bf,
                                                    float* __restrict__ sup) {
    __shared__ float smean[256];
    int t = threadIdx.x;
    float s = 0.f;
    for (int g = 0; g < G_GRAPHS; g++) s += pooled[(size_t)g * H + t];
    smean[t] = s / (float)G_GRAPHS;
    __syncthreads();
    float acc = 0.f;
    for (int k = 0; k < H; k++) acc += smean[k] * Wf[(size_t)t * H + k];
    acc += bf[t];
    sup[t] = fmaxf(acc, 0.f);
}

__global__ __launch_bounds__(256) void writeout(const float* __restrict__ pooled,
                                                const float* __restrict__ sup,
                                                float* __restrict__ out) {
    int idx = blockIdx.x * 256 + threadIdx.x;   // G*2H = 65536
    int g = idx >> 9, c = idx & 511;
    out[idx] = (c < H) ? pooled[(size_t)g * H + c] : sup[c - H];
}

// ---------------------------------------------------------------- launcher
extern "C" void kernel_launch(void* const* d_in, const int* in_sizes, int n_in,
                              void* d_out, int out_size, void* d_ws, size_t ws_size,
                              hipStream_t stream) {
    const float* x      = (const float*)d_in[0];
    const int*   ei     = (const int*)d_in[1];
    const int*   batch  = (const int*)d_in[2];
    const float* W0     = (const float*)d_in[3];
    const float* a_src0 = (const float*)d_in[4];
    const float* a_dst0 = (const float*)d_in[5];
    const float* b0     = (const float*)d_in[6];
    const float* W1     = (const float*)d_in[7];
    const float* a_src1 = (const float*)d_in[8];
    const float* a_dst1 = (const float*)d_in[9];
    const float* b1     = (const float*)d_in[10];
    const float* W_ih   = (const float*)d_in[11];
    const float* b_ih   = (const float*)d_in[13];
    const float* b_hh   = (const float*)d_in[14];
    const float* Wf     = (const float*)d_in[15];
    const float* bf     = (const float*)d_in[16];
    float* out = (float*)d_out;

    char* p = (char*)d_ws;
    auto alloc = [&](size_t bytes) -> void* {
        void* r = (void*)p;
        p += (bytes + 255) & ~(size_t)255;
        return r;
    };
    u16*   xp_bf  = (u16*)alloc((size_t)N_PAD * H * 2);
    u16*   h_bf   = (u16*)alloc((size_t)N_PAD * H * 2);
    u16*   x_bf   = (u16*)alloc((size_t)N_PAD * IN_CH * 2);   // dead after gemm L0
    u8*    xp8    = (u8*)x_bf;                                // alias: N_PAD*H*1
    u16*   gatesC = (u16*)alloc((size_t)N_PAD * 3 * H * 2);   // 77 MB (ws = 256 MB)
    u16*   W0t    = (u16*)alloc((size_t)H * IN_CH * 2);
    u16*   W1t    = (u16*)alloc((size_t)H * H * 2);
    u16*   Wih_bf = (u16*)alloc((size_t)3 * H * H * 2);
    float* s_src  = (float*)alloc((size_t)N_NODES * 4);
    float* s_dst  = (float*)alloc((size_t)N_NODES * 4);
    int2*  rec    = (int2*)alloc((size_t)N_EDGES * 8);
    int*   eidsSrc= (int*)alloc((size_t)ET * 4);
    int*   indptr = (int*)alloc((size_t)(N_NODES + 1) * 4);
    int*   gBkt   = (int*)alloc((size_t)(NB + 1) * 4);
    int*   bktOff = (int*)alloc((size_t)(NB + 1) * 4);
    int*   bktCur = (int*)alloc((size_t)(NB + 1) * 4);
    float* pooled = (float*)alloc((size_t)G_GRAPHS * H * 4);
    float* sup    = (float*)alloc((size_t)H * 4);

    // ---- CSR build (bucketed counting sort) ----
    hipMemsetAsync(gBkt, 0, (size_t)NB * 4, stream);
    bucket_hist<<<NB, 256, 0, stream>>>(ei, gBkt);
    bucket_scan<<<1, 512, 0, stream>>>(gBkt, bktOff, bktCur);
    bucket_scatter<<<(N_EDGES + 256 * EPT - 1) / (256 * EPT), 256, 0, stream>>>(ei, bktCur, rec);
    build_csr<<<NB, 256, 0, stream>>>(rec, bktOff, indptr, eidsSrc);

    // conversions
    prep_kernel<<<dim3((N_NODES * IN_CH / 4 + 255) / 256, 4), 256, 0, stream>>>(
        x, W_ih, W0, W1, x_bf, Wih_bf, W0t, W1t);

    const int MB = (N_NODES + 127) / 128;            // 391
    const int WB = N_NODES / 4;                      // 12500
    // GAT layer 0
    gemm_wide<<<dim3(MB, 1), 256, 0, stream>>>(x_bf, W0t, xp_bf, N_NODES, IN_CH, H);
    sdot_fp8<<<WB, 256, 0, stream>>>(xp_bf, a_src0, a_dst0, s_src, s_dst, xp8);
    gat_agg_fp8<<<WB, 256, 0, stream>>>(xp8, s_src, s_dst, indptr, eidsSrc, b0, h_bf);
    // GAT layer 1
    gemm_wide<<<dim3(MB, 1), 256, 0, stream>>>(h_bf, W1t, xp_bf, N_NODES, H, H);
    sdot_fp8<<<WB, 256, 0, stream>>>(xp_bf, a_src1, a_dst1, s_src, s_dst, xp8);
    gat_agg_fp8<<<WB, 256, 0, stream>>>(xp8, s_src, s_dst, indptr, eidsSrc, b1, h_bf);
    // GRU (single GEMM) + fused pooling
    hipMemsetAsync(pooled, 0, (size_t)G_GRAPHS * H * 4, stream);
    gemm_wide<<<dim3(MB, 3), 256, 0, stream>>>(h_bf, Wih_bf, gatesC, N_NODES, H, 3 * H);
    gru_gates_pool<<<(N_NODES + 15) / 16, 256, 0, stream>>>(gatesC, b_ih, b_hh, batch, pooled);
    // super node + writeout
    super_kernel<<<1, 256, 0, stream>>>(pooled, Wf, bf, sup);
    writeout<<<(G_GRAPHS * 2 * H) / 256, 256, 0, stream>>>(pooled, sup, out);
}

// Round 10
// 356.114 us; speedup vs baseline: 1.8699x; 1.8699x over previous
//
#include <hip/hip_runtime.h>
#include <hip/hip_fp16.h>
#include <math.h>

#define N_NODES 50000
#define N_PAD   50176            // 392*128, padded rows for unguarded GEMM A-tiles
#define N_EDGES 800000
#define ET (N_EDGES + N_NODES)   // 850000 with self loops
#define IN_CH 128
#define H 256
#define G_GRAPHS 128
#define NEG_SLOPE 0.2f
#define NB 391                   // node buckets of 128: ceil(50000/128)

typedef __attribute__((ext_vector_type(8))) short short8;
typedef __attribute__((ext_vector_type(4))) float f32x4;
typedef __attribute__((ext_vector_type(2))) float f32x2;
typedef unsigned short u16;
typedef unsigned char u8;

#if __has_builtin(__builtin_amdgcn_cvt_f32_fp8) && __has_builtin(__builtin_amdgcn_cvt_pk_fp8_f32)
#define USE_FP8_BUILTINS 1
#else
#define USE_FP8_BUILTINS 0
#endif
#if USE_FP8_BUILTINS && __has_builtin(__builtin_amdgcn_cvt_pk_f32_fp8)
#define HAVE_PK_DEC 1
#else
#define HAVE_PK_DEC 0
#endif

__device__ inline u16 f2bf(float v) {
    unsigned u = __float_as_uint(v);
    unsigned r = (u + 0x7FFFu + ((u >> 16) & 1u)) >> 16;
    return (u16)r;
}
__device__ inline float bf2f(u16 v) {
    return __uint_as_float(((unsigned)v) << 16);
}

// ---- fp8 e4m3fn helpers -------------------------------------------------
#if USE_FP8_BUILTINS
#define FP8_WSCALE 1.0f
__device__ inline unsigned fp8_pack4(float a, float b, float c, float d) {
    int v = 0;
    v = __builtin_amdgcn_cvt_pk_fp8_f32(a, b, v, false);
    v = __builtin_amdgcn_cvt_pk_fp8_f32(c, d, v, true);
    return (unsigned)v;
}
__device__ inline void fp8_dec4(unsigned rv, float& f0, float& f1, float& f2, float& f3) {
#if HAVE_PK_DEC
    f32x2 lo = __builtin_amdgcn_cvt_pk_f32_fp8((int)rv, false);
    f32x2 hi = __builtin_amdgcn_cvt_pk_f32_fp8((int)rv, true);
    f0 = lo.x; f1 = lo.y; f2 = hi.x; f3 = hi.y;
#else
    f0 = __builtin_amdgcn_cvt_f32_fp8((int)rv, 0);
    f1 = __builtin_amdgcn_cvt_f32_fp8((int)rv, 1);
    f2 = __builtin_amdgcn_cvt_f32_fp8((int)rv, 2);
    f3 = __builtin_amdgcn_cvt_f32_fp8((int)rv, 3);
#endif
}
#else
#define FP8_WSCALE 256.0f
__device__ inline u8 fp8_enc1(float f) {
    unsigned u = __float_as_uint(f);
    unsigned s = (u >> 31) << 7;
    float a = fabsf(f);
    if (a >= 448.f) return (u8)(s | 0x7E);
    unsigned bits = __float_as_uint(a);
    int exp = (int)((bits >> 23) & 255) - 127;
    unsigned m23 = bits & 0x7fffff;
    if (exp < -6) {
        int m = (int)rintf(a * 512.f);
        if (m >= 8) return (u8)(s | (1 << 3));
        return (u8)(s | m);
    }
    int e8 = exp + 7;
    unsigned m = m23 >> 20, rem = m23 & 0xFFFFF;
    if (rem > 0x80000 || (rem == 0x80000 && (m & 1))) m++;
    if (m == 8) { m = 0; e8++; }
    if (e8 > 15 || (e8 == 15 && m == 7)) return (u8)(s | 0x7E);
    return (u8)(s | (e8 << 3) | m);
}
__device__ inline unsigned fp8_pack4(float a, float b, float c, float d) {
    return (unsigned)fp8_enc1(a) | ((unsigned)fp8_enc1(b) << 8) |
           ((unsigned)fp8_enc1(c) << 16) | ((unsigned)fp8_enc1(d) << 24);
}
// half-trick decode: e4m3 bits in f16 give value * 2^-8 (fold 256 into weights)
__device__ inline void fp8_dec4(unsigned rv, float& f0, float& f1, float& f2, float& f3) {
    unsigned hA = ((rv & 0x00800080u) << 8) | ((rv & 0x007f007fu) << 7);
    unsigned rs = rv >> 8;
    unsigned hB = ((rs & 0x00800080u) << 8) | ((rs & 0x007f007fu) << 7);
    __half2 a = *(__half2*)&hA;
    __half2 b = *(__half2*)&hB;
    f0 = __low2float(a);  f2 = __high2float(a);
    f1 = __low2float(b);  f3 = __high2float(b);
}
#endif

// async global->LDS 16B copy (dest must be wave-uniform base + lane*16)
__device__ inline void async_cp16(const u16* g, u16* l) {
    __builtin_amdgcn_global_load_lds(
        (const __attribute__((address_space(1))) unsigned int*)g,
        (__attribute__((address_space(3))) unsigned int*)l,
        16, 0, 0);
}

// =========================== CSR build (bucketed) ========================
__global__ __launch_bounds__(256) void bucket_hist(const int* __restrict__ ei,
                                                   int* __restrict__ gcnt) {
    __shared__ int h[NB];
    int t = threadIdx.x;
    for (int b = t; b < NB; b += 256) h[b] = 0;
    __syncthreads();
    for (int e = blockIdx.x * 256 + t; e < N_EDGES; e += gridDim.x * 256)
        atomicAdd(&h[ei[N_EDGES + e] >> 7], 1);
    __syncthreads();
    for (int b = t; b < NB; b += 256)
        if (h[b]) atomicAdd(&gcnt[b], h[b]);
}

__global__ __launch_bounds__(512) void bucket_scan(const int* __restrict__ gcnt,
                                                   int* __restrict__ off,
                                                   int* __restrict__ cur) {
    __shared__ int s[NB + 1];
    int t = threadIdx.x;
    if (t < NB) s[t] = gcnt[t];
    __syncthreads();
    if (t == 0) {
        int a = 0;
        for (int b = 0; b < NB; b++) { int c = s[b]; s[b] = a; a += c; }
        s[NB] = a;
    }
    __syncthreads();
    if (t <= NB) { off[t] = s[t]; if (t < NB) cur[t] = s[t]; }
}

#define EPT 16
__global__ __launch_bounds__(256) void bucket_scatter(const int* __restrict__ ei,
                                                      int* __restrict__ bucketCur,
                                                      int2* __restrict__ rec) {
    __shared__ int cnt[NB];
    __shared__ int base[NB];
    int t = threadIdx.x;
    for (int b = t; b < NB; b += 256) cnt[b] = 0;
    __syncthreads();
    int e0 = blockIdx.x * (256 * EPT);
    int sa[EPT], da[EPT], rk[EPT];
#pragma unroll
    for (int k = 0; k < EPT; k++) {
        int e = e0 + k * 256 + t;
        if (e < N_EDGES) {
            sa[k] = ei[e];
            da[k] = ei[N_EDGES + e];
            rk[k] = atomicAdd(&cnt[da[k] >> 7], 1);
        }
    }
    __syncthreads();
    for (int b = t; b < NB; b += 256) {
        int c = cnt[b];
        base[b] = c ? atomicAdd(&bucketCur[b], c) : 0;
    }
    __syncthreads();
#pragma unroll
    for (int k = 0; k < EPT; k++) {
        int e = e0 + k * 256 + t;
        if (e < N_EDGES) rec[base[da[k] >> 7] + rk[k]] = make_int2(sa[k], da[k]);
    }
}

// one block per bucket: node histogram + local scan + indptr + CSR scatter
__global__ __launch_bounds__(256) void build_csr(const int2* __restrict__ rec,
                                                 const int* __restrict__ off,
                                                 int* __restrict__ indptr,
                                                 int* __restrict__ eidsSrc) {
    __shared__ int cnt[128];
    __shared__ int scn[128];
    __shared__ int cur[128];
    int b = blockIdx.x, t = threadIdx.x;
    int nInB = N_NODES - b * 128;
    if (nInB > 128) nInB = 128;
    if (t < 128) cnt[t] = 0;
    __syncthreads();
    int lo = off[b], hi = off[b + 1];
    for (int i = lo + t; i < hi; i += 256) atomicAdd(&cnt[rec[i].y & 127], 1);
    __syncthreads();
    if (t < 128) scn[t] = cnt[t] + 1;   // +1 self loop
    __syncthreads();
    for (int o = 1; o < 128; o <<= 1) {
        int v = 0;
        if (t < 128 && t >= o) v = scn[t - o];
        __syncthreads();
        if (t < 128 && t >= o) scn[t] += v;
        __syncthreads();
    }
    int base = off[b] + 128 * b;        // edges + self loops before this bucket
    if (t < nInB) {
        int start = base + (t ? scn[t - 1] : 0);
        int node = b * 128 + t;
        indptr[node] = start;
        eidsSrc[start] = node;          // self loop slot
        cur[t] = start + 1;
    }
    if (b == 0 && t == 0) indptr[N_NODES] = ET;
    __syncthreads();
    for (int i = lo + t; i < hi; i += 256) {
        int2 r = rec[i];
        int pos = atomicAdd(&cur[r.y & 127], 1);
        eidsSrc[pos] = r.x;
    }
}

// ------------------------------------------------- combined conversions
__global__ __launch_bounds__(256) void prep_kernel(const float* __restrict__ x,
                                                   const float* __restrict__ Wih,
                                                   const float* __restrict__ W0,
                                                   const float* __restrict__ W1,
                                                   u16* __restrict__ x_bf,
                                                   u16* __restrict__ Wih_bf,
                                                   u16* __restrict__ W0t,
                                                   u16* __restrict__ W1t) {
    int i = blockIdx.x * 256 + threadIdx.x;
    int seg = blockIdx.y;
    if (seg == 0) {
        if (i < N_NODES * IN_CH / 4) {
            float4 v = *(const float4*)&x[i * 4];
            ushort4 o = {f2bf(v.x), f2bf(v.y), f2bf(v.z), f2bf(v.w)};
            *(ushort4*)&x_bf[i * 4] = o;
        }
    } else if (seg == 1) {
        if (i < 3 * H * H / 4) {
            float4 v = *(const float4*)&Wih[i * 4];
            ushort4 o = {f2bf(v.x), f2bf(v.y), f2bf(v.z), f2bf(v.w)};
            *(ushort4*)&Wih_bf[i * 4] = o;
        }
    } else if (seg == 2) {
        if (i < IN_CH * H) {
            int k = i / H, n = i % H;
            W0t[(size_t)n * IN_CH + k] = f2bf(W0[i]);
        }
    } else {
        if (i < H * H) {
            int k = i / H, n = i % H;
            W1t[(size_t)n * H + k] = f2bf(W1[i]);
        }
    }
}

// ------------------------------------------------------------ MFMA GEMM (wide)
// C[M,Ntot] = A[M,K](bf16) @ Bt[Ntot,K]^T (bf16), fp32 acc, bf16 out.
// 128x256 tile, BK=32, 256 thr = 4 waves (2m x 2n of 64x128).
// XOR-swizzled LDS chunk placement (conflict-minimal, global_load_lds-safe).
// launch_bounds(256,2): acc tile = 128 regs/thread; (256,4) forces spill
// (round 9: 1 GB scratch traffic/dispatch, 232 us). DO NOT raise.
__global__ __launch_bounds__(256, 2) void gemm_wide(const u16* __restrict__ A,
                                                    const u16* __restrict__ Bt,
                                                    u16* __restrict__ C,
                                                    int M, int K, int Ntot) {
    __shared__ u16 As[128][32];   // 8 KB, NO pad (global_load_lds contiguity)
    __shared__ u16 Bs[256][32];   // 16 KB
    int t = threadIdx.x;
    int m0 = blockIdx.x * 128;
    int n0 = blockIdx.y * 256;
    int wave = t >> 6, lane = t & 63;
    int wm = (wave >> 1) * 64, wn = (wave & 1) * 128;
    int lrow = lane & 15;
    int lq = lane >> 4;

    f32x4 acc[4][8];
#pragma unroll
    for (int i = 0; i < 4; i++)
#pragma unroll
        for (int j = 0; j < 8; j++)
            acc[i][j] = (f32x4){0.f, 0.f, 0.f, 0.f};

    // thread t stages slot (r0, t&3); swizzle -> fetch global k-quad qs
    int r0 = t >> 2;
    int qs = (t & 3) ^ ((t >> 3) & 3);   // (t&3) ^ ((r0>>1)&3)
    const u16* gA0 = A + (size_t)(m0 + r0) * K + qs * 8;
    const u16* gA1 = gA0 + (size_t)64 * K;
    const u16* gB0 = Bt + (size_t)(n0 + r0) * K + qs * 8;
    const u16* gB1 = gB0 + (size_t)64 * K;
    const u16* gB2 = gB0 + (size_t)128 * K;
    const u16* gB3 = gB0 + (size_t)192 * K;
    u16* lA0 = &As[0][0] + t * 8;
    u16* lA1 = lA0 + 256 * 8;
    u16* lB0 = &Bs[0][0] + t * 8;
    u16* lB1 = lB0 + 256 * 8;
    u16* lB2 = lB0 + 512 * 8;
    u16* lB3 = lB0 + 768 * 8;

    int swz8 = (lq ^ ((lrow >> 1) & 3)) * 8;   // reader-side swizzled column

    for (int k0 = 0; k0 < K; k0 += 32) {
        __syncthreads();
        async_cp16(gA0 + k0, lA0);
        async_cp16(gA1 + k0, lA1);
        async_cp16(gB0 + k0, lB0);
        async_cp16(gB1 + k0, lB1);
        async_cp16(gB2 + k0, lB2);
        async_cp16(gB3 + k0, lB3);
        __syncthreads();
        short8 af[4], bfr[8];
#pragma unroll
        for (int i = 0; i < 4; i++)
            af[i] = *(const short8*)&As[wm + i * 16 + lrow][swz8];
#pragma unroll
        for (int j = 0; j < 8; j++)
            bfr[j] = *(const short8*)&Bs[wn + j * 16 + lrow][swz8];
#pragma unroll
        for (int i = 0; i < 4; i++)
#pragma unroll
            for (int j = 0; j < 8; j++)
                acc[i][j] = __builtin_amdgcn_mfma_f32_16x16x32_bf16(af[i], bfr[j], acc[i][j], 0, 0, 0);
    }
    // C/D layout: col = lane&15, row = (lane>>4)*4 + reg
#pragma unroll
    for (int i = 0; i < 4; i++) {
#pragma unroll
        for (int reg = 0; reg < 4; reg++) {
            int gm = m0 + wm + i * 16 + lq * 4 + reg;
            if (gm < M) {
#pragma unroll
                for (int j = 0; j < 8; j++) {
                    int gn = n0 + wn + j * 16 + lrow;
                    C[(size_t)gm * Ntot + gn] = f2bf(acc[i][j][reg]);
                }
            }
        }
    }
}

// ------------------------------------------- attention pre-dots + fp8 encode
__global__ __launch_bounds__(256) void sdot_fp8(const u16* __restrict__ xp,
                                                const float* __restrict__ a_src,
                                                const float* __restrict__ a_dst,
                                                float* __restrict__ s_src,
                                                float* __restrict__ s_dst,
                                                u8* __restrict__ xp8) {
    int wave = threadIdx.x >> 6, lane = threadIdx.x & 63;
    int n = blockIdx.x * 4 + wave;
    int col = lane << 2;
    ushort4 v = *(const ushort4*)&xp[(size_t)n * H + col];
    float4 a1 = *(const float4*)&a_src[col];
    float4 a2 = *(const float4*)&a_dst[col];
    float x0 = bf2f(v.x), x1 = bf2f(v.y), x2 = bf2f(v.z), x3 = bf2f(v.w);
    *(unsigned*)&xp8[(size_t)n * H + col] = fp8_pack4(x0, x1, x2, x3);
    float d1 = x0 * a1.x + x1 * a1.y + x2 * a1.z + x3 * a1.w;
    float d2 = x0 * a2.x + x1 * a2.y + x2 * a2.z + x3 * a2.w;
#pragma unroll
    for (int off = 32; off; off >>= 1) {
        d1 += __shfl_xor(d1, off);
        d2 += __shfl_xor(d2, off);
    }
    if (lane == 0) { s_src[n] = d1; s_dst[n] = d2; }
}

// --------------------------------------------------------- GAT aggregation
// wave per node; CSR stores src directly; fp8 value gather; 16-deep batching
__global__ __launch_bounds__(256) void gat_agg_fp8(const u8* __restrict__ xp8,
                                                   const float* __restrict__ s_src,
                                                   const float* __restrict__ s_dst,
                                                   const int* __restrict__ indptr,
                                                   const int* __restrict__ eidsSrc,
                                                   const float* __restrict__ bias,
                                                   u16* __restrict__ out) {
    __shared__ int2 sSW[4][64];
    int wave = threadIdx.x >> 6, lane = threadIdx.x & 63;
    int n = blockIdx.x * 4 + wave;
    int start = indptr[n];
    int deg = indptr[n + 1] - start;
    float sdn = s_dst[n];
    int col = lane << 2;
    float a0 = 0.f, a1 = 0.f, a2 = 0.f, a3 = 0.f;

    if (deg <= 64) {
        int s = 0;
        float v = -1e30f;
        if (lane < deg) {
            s = eidsSrc[start + lane];
            float u = s_src[s] + sdn;
            v = (u >= 0.f) ? u : NEG_SLOPE * u;
        }
        float m = v;
#pragma unroll
        for (int off = 32; off; off >>= 1) m = fmaxf(m, __shfl_xor(m, off));
        float pw = (lane < deg) ? expf(v - m) : 0.f;
        float dsum = pw;
#pragma unroll
        for (int off = 32; off; off >>= 1) dsum += __shfl_xor(dsum, off);
        float w = pw * (FP8_WSCALE / dsum);
        sSW[wave][lane] = make_int2(s * H, __float_as_int(w));   // premul row offset
        int j = 0;
        for (; j + 16 <= deg; j += 16) {
            unsigned rv[16];
            float wv[16];
#pragma unroll
            for (int k = 0; k < 16; k++) {
                int2 sw = sSW[wave][j + k];
                wv[k] = __int_as_float(sw.y);
                rv[k] = *(const unsigned*)&xp8[(size_t)(unsigned)sw.x + col];
            }
#pragma unroll
            for (int k = 0; k < 16; k++) {
                float f0, f1, f2, f3;
                fp8_dec4(rv[k], f0, f1, f2, f3);
                a0 += wv[k] * f0; a1 += wv[k] * f1;
                a2 += wv[k] * f2; a3 += wv[k] * f3;
            }
        }
        if (j + 8 <= deg) {
            unsigned rv[8];
            float wv[8];
#pragma unroll
            for (int k = 0; k < 8; k++) {
                int2 sw = sSW[wave][j + k];
                wv[k] = __int_as_float(sw.y);
                rv[k] = *(const unsigned*)&xp8[(size_t)(unsigned)sw.x + col];
            }
#pragma unroll
            for (int k = 0; k < 8; k++) {
                float f0, f1, f2, f3;
                fp8_dec4(rv[k], f0, f1, f2, f3);
                a0 += wv[k] * f0; a1 += wv[k] * f1;
                a2 += wv[k] * f2; a3 += wv[k] * f3;
            }
            j += 8;
        }
        for (; j < deg; j++) {
            int2 sw = sSW[wave][j];
            float wj = __int_as_float(sw.y);
            unsigned rv = *(const unsigned*)&xp8[(size_t)(unsigned)sw.x + col];
            float f0, f1, f2, f3;
            fp8_dec4(rv, f0, f1, f2, f3);
            a0 += wj * f0; a1 += wj * f1; a2 += wj * f2; a3 += wj * f3;
        }
    } else {
        float m = -1e30f;
        for (int i = lane; i < deg; i += 64) {
            int s = eidsSrc[start + i];
            float u = s_src[s] + sdn;
            u = (u >= 0.f) ? u : NEG_SLOPE * u;
            m = fmaxf(m, u);
        }
#pragma unroll
        for (int off = 32; off; off >>= 1) m = fmaxf(m, __shfl_xor(m, off));
        float dsum = 0.f;
        for (int i = lane; i < deg; i += 64) {
            int s = eidsSrc[start + i];
            float u = s_src[s] + sdn;
            u = (u >= 0.f) ? u : NEG_SLOPE * u;
            dsum += expf(u - m);
        }
#pragma unroll
        for (int off = 32; off; off >>= 1) dsum += __shfl_xor(dsum, off);
        float dinv = FP8_WSCALE / dsum;
        for (int base = 0; base < deg; base += 64) {
            int cnt = min(64, deg - base);
            int s = 0; float w = 0.f;
            if (lane < cnt) {
                s = eidsSrc[start + base + lane];
                float u = s_src[s] + sdn;
                u = (u >= 0.f) ? u : NEG_SLOPE * u;
                w = expf(u - m) * dinv;
            }
            sSW[wave][lane] = make_int2(s * H, __float_as_int(w));
            for (int j = 0; j < cnt; j++) {
                int2 sw = sSW[wave][j];
                float wj = __int_as_float(sw.y);
                unsigned rv = *(const unsigned*)&xp8[(size_t)(unsigned)sw.x + col];
                float f0, f1, f2, f3;
                fp8_dec4(rv, f0, f1, f2, f3);
                a0 += wj * f0; a1 += wj * f1; a2 += wj * f2; a3 += wj * f3;
            }
        }
    }
    float4 bv = *(const float4*)&bias[col];
    ushort4 o;
    o.x = f2bf(fmaxf(a0 + bv.x, 0.f));
    o.y = f2bf(fmaxf(a1 + bv.y, 0.f));
    o.z = f2bf(fmaxf(a2 + bv.z, 0.f));
    o.w = f2bf(fmaxf(a3 + bv.w, 0.f));
    *(ushort4*)&out[(size_t)n * H + col] = o;
}

// ------------------------------------------------- GRU gates + pooling (fused)
__global__ __launch_bounds__(256) void gru_gates_pool(const u16* __restrict__ gates,
                                                      const float* __restrict__ b_ih,
                                                      const float* __restrict__ b_hh,
                                                      const int* __restrict__ batch,
                                                      float* __restrict__ pooled) {
    int t = threadIdx.x;
    int i0 = blockIdx.x * 16;
    if (i0 >= N_NODES) return;
    float bir = b_ih[t], biz = b_ih[256 + t], bin_ = b_ih[512 + t];
    float bhr = b_hh[t], bhz = b_hh[256 + t], bhn = b_hh[512 + t];
    int iend = min(16, N_NODES - i0);
    float acc = 0.f;
    int cur_g = batch[i0];
    for (int i = 0; i < iend; i++) {
        size_t row = (size_t)(i0 + i) * 768;
        float ir = bf2f(gates[row + t]);
        float iz = bf2f(gates[row + 256 + t]);
        float in_ = bf2f(gates[row + 512 + t]);
        float r = 1.f / (1.f + expf(-(ir + bir + bhr)));
        float z = 1.f / (1.f + expf(-(iz + biz + bhz)));
        float nn = tanhf(in_ + bin_ + r * bhn);
        float h = (1.f - z) * nn;
        int g = batch[i0 + i];
        if (g != cur_g) {
            atomicAdd(&pooled[(size_t)cur_g * H + t], acc);
            acc = 0.f;
            cur_g = g;
        }
        acc += h;
    }
    atomicAdd(&pooled[(size_t)cur_g * H + t], acc);
}

// --------------------------------------------------------------- super node
__global__ __launch_bounds__(256) void super_kernel(const float* __restrict__ pooled,
                                                    const float* __restrict__ Wf,
                                                    const float* __restrict__ bf,
                                                    float* __restrict__ sup) {
    __shared__ float smean[256];
    int t = threadIdx.x;
    float s = 0.f;
    for (int g = 0; g < G_GRAPHS; g++) s += pooled[(size_t)g * H + t];
    smean[t] = s / (float)G_GRAPHS;
    __syncthreads();
    float acc = 0.f;
    for (int k = 0; k < H; k++) acc += smean[k] * Wf[(size_t)t * H + k];
    acc += bf[t];
    sup[t] = fmaxf(acc, 0.f);
}

__global__ __launch_bounds__(256) void writeout(const float* __restrict__ pooled,
                                                const float* __restrict__ sup,
                                                float* __restrict__ out) {
    int idx = blockIdx.x * 256 + threadIdx.x;   // G*2H = 65536
    int g = idx >> 9, c = idx & 511;
    out[idx] = (c < H) ? pooled[(size_t)g * H + c] : sup[c - H];
}

// ---------------------------------------------------------------- launcher
extern "C" void kernel_launch(void* const* d_in, const int* in_sizes, int n_in,
                              void* d_out, int out_size, void* d_ws, size_t ws_size,
                              hipStream_t stream) {
    const float* x      = (const float*)d_in[0];
    const int*   ei     = (const int*)d_in[1];
    const int*   batch  = (const int*)d_in[2];
    const float* W0     = (const float*)d_in[3];
    const float* a_src0 = (const float*)d_in[4];
    const float* a_dst0 = (const float*)d_in[5];
    const float* b0     = (const float*)d_in[6];
    const float* W1     = (const float*)d_in[7];
    const float* a_src1 = (const float*)d_in[8];
    const float* a_dst1 = (const float*)d_in[9];
    const float* b1     = (const float*)d_in[10];
    const float* W_ih   = (const float*)d_in[11];
    const float* b_ih   = (const float*)d_in[13];
    const float* b_hh   = (const float*)d_in[14];
    const float* Wf     = (const float*)d_in[15];
    const float* bf     = (const float*)d_in[16];
    float* out = (float*)d_out;

    char* p = (char*)d_ws;
    auto alloc = [&](size_t bytes) -> void* {
        void* r = (void*)p;
        p += (bytes + 255) & ~(size_t)255;
        return r;
    };
    u16*   xp_bf  = (u16*)alloc((size_t)N_PAD * H * 2);
    u16*   h_bf   = (u16*)alloc((size_t)N_PAD * H * 2);
    u16*   x_bf   = (u16*)alloc((size_t)N_PAD * IN_CH * 2);   // dead after gemm L0
    u8*    xp8    = (u8*)x_bf;                                // alias: N_PAD*H*1
    u16*   gatesC = (u16*)alloc((size_t)N_PAD * 3 * H * 2);   // 77 MB (ws = 256 MB)
    u16*   W0t    = (u16*)alloc((size_t)H * IN_CH * 2);
    u16*   W1t    = (u16*)alloc((size_t)H * H * 2);
    u16*   Wih_bf = (u16*)alloc((size_t)3 * H * H * 2);
    float* s_src  = (float*)alloc((size_t)N_NODES * 4);
    float* s_dst  = (float*)alloc((size_t)N_NODES * 4);
    int2*  rec    = (int2*)alloc((size_t)N_EDGES * 8);
    int*   eidsSrc= (int*)alloc((size_t)ET * 4);
    int*   indptr = (int*)alloc((size_t)(N_NODES + 1) * 4);
    int*   gBkt   = (int*)alloc((size_t)(NB + 1) * 4);
    int*   bktOff = (int*)alloc((size_t)(NB + 1) * 4);
    int*   bktCur = (int*)alloc((size_t)(NB + 1) * 4);
    float* pooled = (float*)alloc((size_t)G_GRAPHS * H * 4);
    float* sup    = (float*)alloc((size_t)H * 4);

    // ---- CSR build (bucketed counting sort) ----
    hipMemsetAsync(gBkt, 0, (size_t)NB * 4, stream);
    bucket_hist<<<NB, 256, 0, stream>>>(ei, gBkt);
    bucket_scan<<<1, 512, 0, stream>>>(gBkt, bktOff, bktCur);
    bucket_scatter<<<(N_EDGES + 256 * EPT - 1) / (256 * EPT), 256, 0, stream>>>(ei, bktCur, rec);
    build_csr<<<NB, 256, 0, stream>>>(rec, bktOff, indptr, eidsSrc);

    // conversions
    prep_kernel<<<dim3((N_NODES * IN_CH / 4 + 255) / 256, 4), 256, 0, stream>>>(
        x, W_ih, W0, W1, x_bf, Wih_bf, W0t, W1t);

    const int MB = (N_NODES + 127) / 128;            // 391
    const int WB = N_NODES / 4;                      // 12500
    // GAT layer 0
    gemm_wide<<<dim3(MB, 1), 256, 0, stream>>>(x_bf, W0t, xp_bf, N_NODES, IN_CH, H);
    sdot_fp8<<<WB, 256, 0, stream>>>(xp_bf, a_src0, a_dst0, s_src, s_dst, xp8);
    gat_agg_fp8<<<WB, 256, 0, stream>>>(xp8, s_src, s_dst, indptr, eidsSrc, b0, h_bf);
    // GAT layer 1
    gemm_wide<<<dim3(MB, 1), 256, 0, stream>>>(h_bf, W1t, xp_bf, N_NODES, H, H);
    sdot_fp8<<<WB, 256, 0, stream>>>(xp_bf, a_src1, a_dst1, s_src, s_dst, xp8);
    gat_agg_fp8<<<WB, 256, 0, stream>>>(xp8, s_src, s_dst, indptr, eidsSrc, b1, h_bf);
    // GRU (single GEMM) + fused pooling
    hipMemsetAsync(pooled, 0, (size_t)G_GRAPHS * H * 4, stream);
    gemm_wide<<<dim3(MB, 3), 256, 0, stream>>>(h_bf, Wih_bf, gatesC, N_NODES, H, 3 * H);
    gru_gates_pool<<<(N_NODES + 15) / 16, 256, 0, stream>>>(gatesC, b_ih, b_hh, batch, pooled);
    // super node + writeout
    super_kernel<<<1, 256, 0, stream>>>(pooled, Wf, bf, sup);
    writeout<<<(G_GRAPHS * 2 * H) / 256, 256, 0, stream>>>(pooled, sup, out);
}

// Round 11
// 337.759 us; speedup vs baseline: 1.9715x; 1.0543x over previous
//
#include <hip/hip_runtime.h>
#include <hip/hip_fp16.h>
#include <math.h>

#define N_NODES 50000
#define N_PAD   50176            // 392*128, padded rows for unguarded GEMM A-tiles
#define N_EDGES 800000
#define ET (N_EDGES + N_NODES)   // 850000 with self loops
#define IN_CH 128
#define H 256
#define G_GRAPHS 128
#define NEG_SLOPE 0.2f
#define NB 391                   // node buckets of 128: ceil(50000/128)

typedef __attribute__((ext_vector_type(8))) short short8;
typedef __attribute__((ext_vector_type(4))) float f32x4;
typedef __attribute__((ext_vector_type(2))) float f32x2;
typedef unsigned short u16;
typedef unsigned char u8;

// fp8 byte layout within a 256-col row is PERMUTED by the 16x16 transpose:
// byte position p holds col T(p), T(p) = ((p&15)<<4) | (p>>4). T is an
// involution. W1t/Wih K-dims and the gat_agg bias arrays are permuted to
// match, so downstream code indexes position-space transparently.

#if __has_builtin(__builtin_amdgcn_cvt_f32_fp8) && __has_builtin(__builtin_amdgcn_cvt_pk_fp8_f32)
#define USE_FP8_BUILTINS 1
#else
#define USE_FP8_BUILTINS 0
#endif
#if USE_FP8_BUILTINS && __has_builtin(__builtin_amdgcn_cvt_pk_f32_fp8)
#define HAVE_PK_DEC 1
#else
#define HAVE_PK_DEC 0
#endif

__device__ inline u16 f2bf(float v) {
    unsigned u = __float_as_uint(v);
    unsigned r = (u + 0x7FFFu + ((u >> 16) & 1u)) >> 16;
    return (u16)r;
}
__device__ inline float bf2f(u16 v) {
    return __uint_as_float(((unsigned)v) << 16);
}

// ---- fp8 e4m3fn helpers -------------------------------------------------
#if USE_FP8_BUILTINS
#define FP8_WSCALE 1.0f
__device__ inline unsigned fp8_pack4(float a, float b, float c, float d) {
    int v = 0;
    v = __builtin_amdgcn_cvt_pk_fp8_f32(a, b, v, false);
    v = __builtin_amdgcn_cvt_pk_fp8_f32(c, d, v, true);
    return (unsigned)v;
}
__device__ inline void fp8_dec4(unsigned rv, float& f0, float& f1, float& f2, float& f3) {
#if HAVE_PK_DEC
    f32x2 lo = __builtin_amdgcn_cvt_pk_f32_fp8((int)rv, false);
    f32x2 hi = __builtin_amdgcn_cvt_pk_f32_fp8((int)rv, true);
    f0 = lo.x; f1 = lo.y; f2 = hi.x; f3 = hi.y;
#else
    f0 = __builtin_amdgcn_cvt_f32_fp8((int)rv, 0);
    f1 = __builtin_amdgcn_cvt_f32_fp8((int)rv, 1);
    f2 = __builtin_amdgcn_cvt_f32_fp8((int)rv, 2);
    f3 = __builtin_amdgcn_cvt_f32_fp8((int)rv, 3);
#endif
}
#else
#define FP8_WSCALE 256.0f
__device__ inline u8 fp8_enc1(float f) {
    unsigned u = __float_as_uint(f);
    unsigned s = (u >> 31) << 7;
    float a = fabsf(f);
    if (a >= 448.f) return (u8)(s | 0x7E);
    unsigned bits = __float_as_uint(a);
    int exp = (int)((bits >> 23) & 255) - 127;
    unsigned m23 = bits & 0x7fffff;
    if (exp < -6) {
        int m = (int)rintf(a * 512.f);
        if (m >= 8) return (u8)(s | (1 << 3));
        return (u8)(s | m);
    }
    int e8 = exp + 7;
    unsigned m = m23 >> 20, rem = m23 & 0xFFFFF;
    if (rem > 0x80000 || (rem == 0x80000 && (m & 1))) m++;
    if (m == 8) { m = 0; e8++; }
    if (e8 > 15 || (e8 == 15 && m == 7)) return (u8)(s | 0x7E);
    return (u8)(s | (e8 << 3) | m);
}
__device__ inline unsigned fp8_pack4(float a, float b, float c, float d) {
    return (unsigned)fp8_enc1(a) | ((unsigned)fp8_enc1(b) << 8) |
           ((unsigned)fp8_enc1(c) << 16) | ((unsigned)fp8_enc1(d) << 24);
}
// half-trick decode: e4m3 bits in f16 give value * 2^-8 (fold 256 into weights)
__device__ inline void fp8_dec4(unsigned rv, float& f0, float& f1, float& f2, float& f3) {
    unsigned hA = ((rv & 0x00800080u) << 8) | ((rv & 0x007f007fu) << 7);
    unsigned rs = rv >> 8;
    unsigned hB = ((rs & 0x00800080u) << 8) | ((rs & 0x007f007fu) << 7);
    __half2 a = *(__half2*)&hA;
    __half2 b = *(__half2*)&hB;
    f0 = __low2float(a);  f2 = __high2float(a);
    f1 = __low2float(b);  f3 = __high2float(b);
}
#endif

// async global->LDS 16B copy (dest must be wave-uniform base + lane*16)
__device__ inline void async_cp16(const u16* g, u16* l) {
    __builtin_amdgcn_global_load_lds(
        (const __attribute__((address_space(1))) unsigned int*)g,
        (__attribute__((address_space(3))) unsigned int*)l,
        16, 0, 0);
}

// =========================== CSR build (bucketed) ========================
__global__ __launch_bounds__(256) void bucket_hist(const int* __restrict__ ei,
                                                   int* __restrict__ gcnt) {
    __shared__ int h[NB];
    int t = threadIdx.x;
    for (int b = t; b < NB; b += 256) h[b] = 0;
    __syncthreads();
    for (int e = blockIdx.x * 256 + t; e < N_EDGES; e += gridDim.x * 256)
        atomicAdd(&h[ei[N_EDGES + e] >> 7], 1);
    __syncthreads();
    for (int b = t; b < NB; b += 256)
        if (h[b]) atomicAdd(&gcnt[b], h[b]);
}

__global__ __launch_bounds__(512) void bucket_scan(const int* __restrict__ gcnt,
                                                   int* __restrict__ off,
                                                   int* __restrict__ cur) {
    __shared__ int s[NB + 1];
    int t = threadIdx.x;
    if (t < NB) s[t] = gcnt[t];
    __syncthreads();
    if (t == 0) {
        int a = 0;
        for (int b = 0; b < NB; b++) { int c = s[b]; s[b] = a; a += c; }
        s[NB] = a;
    }
    __syncthreads();
    if (t <= NB) { off[t] = s[t]; if (t < NB) cur[t] = s[t]; }
}

#define EPT 16
__global__ __launch_bounds__(256) void bucket_scatter(const int* __restrict__ ei,
                                                      int* __restrict__ bucketCur,
                                                      int2* __restrict__ rec) {
    __shared__ int cnt[NB];
    __shared__ int base[NB];
    int t = threadIdx.x;
    for (int b = t; b < NB; b += 256) cnt[b] = 0;
    __syncthreads();
    int e0 = blockIdx.x * (256 * EPT);
    int sa[EPT], da[EPT], rk[EPT];
#pragma unroll
    for (int k = 0; k < EPT; k++) {
        int e = e0 + k * 256 + t;
        if (e < N_EDGES) {
            sa[k] = ei[e];
            da[k] = ei[N_EDGES + e];
            rk[k] = atomicAdd(&cnt[da[k] >> 7], 1);
        }
    }
    __syncthreads();
    for (int b = t; b < NB; b += 256) {
        int c = cnt[b];
        base[b] = c ? atomicAdd(&bucketCur[b], c) : 0;
    }
    __syncthreads();
#pragma unroll
    for (int k = 0; k < EPT; k++) {
        int e = e0 + k * 256 + t;
        if (e < N_EDGES) rec[base[da[k] >> 7] + rk[k]] = make_int2(sa[k], da[k]);
    }
}

// one block per bucket: node histogram + local scan + indptr + CSR scatter
__global__ __launch_bounds__(256) void build_csr(const int2* __restrict__ rec,
                                                 const int* __restrict__ off,
                                                 int* __restrict__ indptr,
                                                 int* __restrict__ eidsSrc) {
    __shared__ int cnt[128];
    __shared__ int scn[128];
    __shared__ int cur[128];
    int b = blockIdx.x, t = threadIdx.x;
    int nInB = N_NODES - b * 128;
    if (nInB > 128) nInB = 128;
    if (t < 128) cnt[t] = 0;
    __syncthreads();
    int lo = off[b], hi = off[b + 1];
    for (int i = lo + t; i < hi; i += 256) atomicAdd(&cnt[rec[i].y & 127], 1);
    __syncthreads();
    if (t < 128) scn[t] = cnt[t] + 1;   // +1 self loop
    __syncthreads();
    for (int o = 1; o < 128; o <<= 1) {
        int v = 0;
        if (t < 128 && t >= o) v = scn[t - o];
        __syncthreads();
        if (t < 128 && t >= o) scn[t] += v;
        __syncthreads();
    }
    int base = off[b] + 128 * b;        // edges + self loops before this bucket
    if (t < nInB) {
        int start = base + (t ? scn[t - 1] : 0);
        int node = b * 128 + t;
        indptr[node] = start;
        eidsSrc[start] = node;          // self loop slot
        cur[t] = start + 1;
    }
    if (b == 0 && t == 0) indptr[N_NODES] = ET;
    __syncthreads();
    for (int i = lo + t; i < hi; i += 256) {
        int2 r = rec[i];
        int pos = atomicAdd(&cur[r.y & 127], 1);
        eidsSrc[pos] = r.x;
    }
}

// ------------------------------------------------- combined conversions
// seg0: x->x_bf; seg1: Wih K-permuted; seg2: W0 transpose; seg3: W1
// transpose + K-permute; seg4: permuted bias copies.
__global__ __launch_bounds__(256) void prep_kernel(const float* __restrict__ x,
                                                   const float* __restrict__ Wih,
                                                   const float* __restrict__ W0,
                                                   const float* __restrict__ W1,
                                                   const float* __restrict__ b0,
                                                   const float* __restrict__ b1,
                                                   u16* __restrict__ x_bf,
                                                   u16* __restrict__ Wih_bf,
                                                   u16* __restrict__ W0t,
                                                   u16* __restrict__ W1t,
                                                   float* __restrict__ b0p,
                                                   float* __restrict__ b1p) {
    int i = blockIdx.x * 256 + threadIdx.x;
    int seg = blockIdx.y;
    if (seg == 0) {
        if (i < N_NODES * IN_CH / 4) {
            float4 v = *(const float4*)&x[i * 4];
            ushort4 o = {f2bf(v.x), f2bf(v.y), f2bf(v.z), f2bf(v.w)};
            *(ushort4*)&x_bf[i * 4] = o;
        }
    } else if (seg == 1) {
        if (i < 3 * H * H) {
            int r = i >> 8, p = i & 255;
            int c = ((p & 15) << 4) | (p >> 4);
            Wih_bf[(size_t)r * H + p] = f2bf(Wih[(size_t)r * H + c]);
        }
    } else if (seg == 2) {
        if (i < IN_CH * H) {
            int k = i / H, n = i % H;
            W0t[(size_t)n * IN_CH + k] = f2bf(W0[i]);
        }
    } else if (seg == 3) {
        if (i < H * H) {
            int n = i >> 8, p = i & 255;
            int c = ((p & 15) << 4) | (p >> 4);
            W1t[(size_t)n * H + p] = f2bf(W1[(size_t)c * H + n]);
        }
    } else {
        if (i < H) {
            int c = ((i & 15) << 4) | (i >> 4);
            b0p[i] = b0[c];
            b1p[i] = b1[c];
        }
    }
}

// ------------------------------------------------------------ MFMA GEMM (wide)
// C[M,Ntot] = A[M,K](bf16) @ Bt[Ntot,K]^T (bf16), fp32 acc.
// 128x256 tile, BK=32, 256 thr = 4 waves (2m x 2n of 64x128).
// XOR-swizzled LDS chunk placement (conflict-minimal, global_load_lds-safe).
// launch_bounds(256,2): acc tile = 128 regs/thread; (256,4) forces spill
// (round 9: 1 GB scratch traffic/dispatch). DO NOT raise.
// FUSE: Ntot==256, n0==0; epilogue emits permuted fp8 rows (contiguous
// 8B/thread/row stores) + s_src/s_dst dots; bf16 C is not written.
template <bool FUSE>
__global__ __launch_bounds__(256, 2) void gemm_wide(const u16* __restrict__ A,
                                                    const u16* __restrict__ Bt,
                                                    u16* __restrict__ C,
                                                    u8* __restrict__ C8,
                                                    const float* __restrict__ avS,
                                                    const float* __restrict__ avD,
                                                    float* __restrict__ sS,
                                                    float* __restrict__ sD,
                                                    int M, int K, int Ntot) {
    __shared__ u16 As[128][32];   // 8 KB, NO pad (global_load_lds contiguity)
    __shared__ u16 Bs[256][32];   // 16 KB
    __shared__ float rSp[2][128]; // 1 KB (fused dot partials; tiny, always present)
    __shared__ float rDp[2][128];
    int t = threadIdx.x;
    int m0 = blockIdx.x * 128;
    int n0 = blockIdx.y * 256;
    int wave = t >> 6, lane = t & 63;
    int wm = (wave >> 1) * 64, wn = (wave & 1) * 128;
    int lrow = lane & 15;
    int lq = lane >> 4;

    f32x4 acc[4][8];
#pragma unroll
    for (int i = 0; i < 4; i++)
#pragma unroll
        for (int j = 0; j < 8; j++)
            acc[i][j] = (f32x4){0.f, 0.f, 0.f, 0.f};

    // thread t stages slot (r0, t&3); swizzle -> fetch global k-quad qs
    int r0 = t >> 2;
    int qs = (t & 3) ^ ((t >> 3) & 3);   // (t&3) ^ ((r0>>1)&3)
    const u16* gA0 = A + (size_t)(m0 + r0) * K + qs * 8;
    const u16* gA1 = gA0 + (size_t)64 * K;
    const u16* gB0 = Bt + (size_t)(n0 + r0) * K + qs * 8;
    const u16* gB1 = gB0 + (size_t)64 * K;
    const u16* gB2 = gB0 + (size_t)128 * K;
    const u16* gB3 = gB0 + (size_t)192 * K;
    u16* lA0 = &As[0][0] + t * 8;
    u16* lA1 = lA0 + 256 * 8;
    u16* lB0 = &Bs[0][0] + t * 8;
    u16* lB1 = lB0 + 256 * 8;
    u16* lB2 = lB0 + 512 * 8;
    u16* lB3 = lB0 + 768 * 8;

    int swz8 = (lq ^ ((lrow >> 1) & 3)) * 8;   // reader-side swizzled column

    for (int k0 = 0; k0 < K; k0 += 32) {
        __syncthreads();
        async_cp16(gA0 + k0, lA0);
        async_cp16(gA1 + k0, lA1);
        async_cp16(gB0 + k0, lB0);
        async_cp16(gB1 + k0, lB1);
        async_cp16(gB2 + k0, lB2);
        async_cp16(gB3 + k0, lB3);
        __syncthreads();
        short8 af[4], bfr[8];
#pragma unroll
        for (int i = 0; i < 4; i++)
            af[i] = *(const short8*)&As[wm + i * 16 + lrow][swz8];
#pragma unroll
        for (int j = 0; j < 8; j++)
            bfr[j] = *(const short8*)&Bs[wn + j * 16 + lrow][swz8];
#pragma unroll
        for (int i = 0; i < 4; i++)
#pragma unroll
            for (int j = 0; j < 8; j++)
                acc[i][j] = __builtin_amdgcn_mfma_f32_16x16x32_bf16(af[i], bfr[j], acc[i][j], 0, 0, 0);
    }

    // C/D layout: col = lane&15, row = (lane>>4)*4 + reg
    if constexpr (FUSE) {
        float aS[8], aD[8];
#pragma unroll
        for (int j = 0; j < 8; j++) {
            aS[j] = avS[wn + j * 16 + lrow];
            aD[j] = avD[wn + j * 16 + lrow];
        }
        int woff = wn ? 8 : 0;
#pragma unroll
        for (int i = 0; i < 4; i++) {
#pragma unroll
            for (int reg = 0; reg < 4; reg++) {
                float ps = 0.f, pd = 0.f;
#pragma unroll
                for (int j = 0; j < 8; j++) {
                    float v = acc[i][j][reg];
                    ps += v * aS[j];
                    pd += v * aD[j];
                }
                // permuted fp8 row store: byte p = lrow*16 + woff + j
                uint2 pk;
                pk.x = fp8_pack4(acc[i][0][reg], acc[i][1][reg], acc[i][2][reg], acc[i][3][reg]);
                pk.y = fp8_pack4(acc[i][4][reg], acc[i][5][reg], acc[i][6][reg], acc[i][7][reg]);
                int row = m0 + wm + i * 16 + lq * 4 + reg;
                *(uint2*)&C8[(size_t)row * 256 + lrow * 16 + woff] = pk;
#pragma unroll
                for (int msk = 1; msk < 16; msk <<= 1) {
                    ps += __shfl_xor(ps, msk);
                    pd += __shfl_xor(pd, msk);
                }
                if (lrow == 0) {
                    int lr = wm + i * 16 + lq * 4 + reg;
                    rSp[wave & 1][lr] = ps;
                    rDp[wave & 1][lr] = pd;
                }
            }
        }
        __syncthreads();
        if (t < 128) {
            int gm = m0 + t;
            if (gm < M) {
                sS[gm] = rSp[0][t] + rSp[1][t];
                sD[gm] = rDp[0][t] + rDp[1][t];
            }
        }
    } else {
#pragma unroll
        for (int i = 0; i < 4; i++) {
#pragma unroll
            for (int reg = 0; reg < 4; reg++) {
                int gm = m0 + wm + i * 16 + lq * 4 + reg;
                if (gm < M) {
#pragma unroll
                    for (int j = 0; j < 8; j++) {
                        int gn = n0 + wn + j * 16 + lrow;
                        C[(size_t)gm * Ntot + gn] = f2bf(acc[i][j][reg]);
                    }
                }
            }
        }
    }
}

// --------------------------------------------------------- GAT aggregation
// wave per node; CSR stores src directly; fp8 value gather (permuted rows —
// bias array is pre-permuted; out is written in permuted layout, consumed
// by K-permuted W1t/Wih). 16-deep batching.
__global__ __launch_bounds__(256) void gat_agg_fp8(const u8* __restrict__ xp8,
                                                   const float* __restrict__ s_src,
                                                   const float* __restrict__ s_dst,
                                                   const int* __restrict__ indptr,
                                                   const int* __restrict__ eidsSrc,
                                                   const float* __restrict__ bias,
                                                   u16* __restrict__ out) {
    __shared__ int2 sSW[4][64];
    int wave = threadIdx.x >> 6, lane = threadIdx.x & 63;
    int n = blockIdx.x * 4 + wave;
    int start = indptr[n];
    int deg = indptr[n + 1] - start;
    float sdn = s_dst[n];
    int col = lane << 2;
    float a0 = 0.f, a1 = 0.f, a2 = 0.f, a3 = 0.f;

    if (deg <= 64) {
        int s = 0;
        float v = -1e30f;
        if (lane < deg) {
            s = eidsSrc[start + lane];
            float u = s_src[s] + sdn;
            v = (u >= 0.f) ? u : NEG_SLOPE * u;
        }
        float m = v;
#pragma unroll
        for (int off = 32; off; off >>= 1) m = fmaxf(m, __shfl_xor(m, off));
        float pw = (lane < deg) ? expf(v - m) : 0.f;
        float dsum = pw;
#pragma unroll
        for (int off = 32; off; off >>= 1) dsum += __shfl_xor(dsum, off);
        float w = pw * (FP8_WSCALE / dsum);
        sSW[wave][lane] = make_int2(s * H, __float_as_int(w));   // premul row offset
        int j = 0;
        for (; j + 16 <= deg; j += 16) {
            unsigned rv[16];
            float wv[16];
#pragma unroll
            for (int k = 0; k < 16; k++) {
                int2 sw = sSW[wave][j + k];
                wv[k] = __int_as_float(sw.y);
                rv[k] = *(const unsigned*)&xp8[(size_t)(unsigned)sw.x + col];
            }
#pragma unroll
            for (int k = 0; k < 16; k++) {
                float f0, f1, f2, f3;
                fp8_dec4(rv[k], f0, f1, f2, f3);
                a0 += wv[k] * f0; a1 += wv[k] * f1;
                a2 += wv[k] * f2; a3 += wv[k] * f3;
            }
        }
        if (j + 8 <= deg) {
            unsigned rv[8];
            float wv[8];
#pragma unroll
            for (int k = 0; k < 8; k++) {
                int2 sw = sSW[wave][j + k];
                wv[k] = __int_as_float(sw.y);
                rv[k] = *(const unsigned*)&xp8[(size_t)(unsigned)sw.x + col];
            }
#pragma unroll
            for (int k = 0; k < 8; k++) {
                float f0, f1, f2, f3;
                fp8_dec4(rv[k], f0, f1, f2, f3);
                a0 += wv[k] * f0; a1 += wv[k] * f1;
                a2 += wv[k] * f2; a3 += wv[k] * f3;
            }
            j += 8;
        }
        for (; j < deg; j++) {
            int2 sw = sSW[wave][j];
            float wj = __int_as_float(sw.y);
            unsigned rv = *(const unsigned*)&xp8[(size_t)(unsigned)sw.x + col];
            float f0, f1, f2, f3;
            fp8_dec4(rv, f0, f1, f2, f3);
            a0 += wj * f0; a1 += wj * f1; a2 += wj * f2; a3 += wj * f3;
        }
    } else {
        float m = -1e30f;
        for (int i = lane; i < deg; i += 64) {
            int s = eidsSrc[start + i];
            float u = s_src[s] + sdn;
            u = (u >= 0.f) ? u : NEG_SLOPE * u;
            m = fmaxf(m, u);
        }
#pragma unroll
        for (int off = 32; off; off >>= 1) m = fmaxf(m, __shfl_xor(m, off));
        float dsum = 0.f;
        for (int i = lane; i < deg; i += 64) {
            int s = eidsSrc[start + i];
            float u = s_src[s] + sdn;
            u = (u >= 0.f) ? u : NEG_SLOPE * u;
            dsum += expf(u - m);
        }
#pragma unroll
        for (int off = 32; off; off >>= 1) dsum += __shfl_xor(dsum, off);
        float dinv = FP8_WSCALE / dsum;
        for (int base = 0; base < deg; base += 64) {
            int cnt = min(64, deg - base);
            int s = 0; float w = 0.f;
            if (lane < cnt) {
                s = eidsSrc[start + base + lane];
                float u = s_src[s] + sdn;
                u = (u >= 0.f) ? u : NEG_SLOPE * u;
                w = expf(u - m) * dinv;
            }
            sSW[wave][lane] = make_int2(s * H, __float_as_int(w));
            for (int j = 0; j < cnt; j++) {
                int2 sw = sSW[wave][j];
                float wj = __int_as_float(sw.y);
                unsigned rv = *(const unsigned*)&xp8[(size_t)(unsigned)sw.x + col];
                float f0, f1, f2, f3;
                fp8_dec4(rv, f0, f1, f2, f3);
                a0 += wj * f0; a1 += wj * f1; a2 += wj * f2; a3 += wj * f3;
            }
        }
    }
    float4 bv = *(const float4*)&bias[col];
    ushort4 o;
    o.x = f2bf(fmaxf(a0 + bv.x, 0.f));
    o.y = f2bf(fmaxf(a1 + bv.y, 0.f));
    o.z = f2bf(fmaxf(a2 + bv.z, 0.f));
    o.w = f2bf(fmaxf(a3 + bv.w, 0.f));
    *(ushort4*)&out[(size_t)n * H + col] = o;
}

// ------------------------------------------------- GRU gates + pooling (fused)
__global__ __launch_bounds__(256) void gru_gates_pool(const u16* __restrict__ gates,
                                                      const float* __restrict__ b_ih,
                                                      const float* __restrict__ b_hh,
                                                      const int* __restrict__ batch,
                                                      float* __restrict__ pooled) {
    int t = threadIdx.x;
    int i0 = blockIdx.x * 16;
    if (i0 >= N_NODES) return;
    float bir = b_ih[t], biz = b_ih[256 + t], bin_ = b_ih[512 + t];
    float bhr = b_hh[t], bhz = b_hh[256 + t], bhn = b_hh[512 + t];
    int iend = min(16, N_NODES - i0);
    float acc = 0.f;
    int cur_g = batch[i0];
    for (int i = 0; i < iend; i++) {
        size_t row = (size_t)(i0 + i) * 768;
        float ir = bf2f(gates[row + t]);
        float iz = bf2f(gates[row + 256 + t]);
        float in_ = bf2f(gates[row + 512 + t]);
        float r = 1.f / (1.f + expf(-(ir + bir + bhr)));
        float z = 1.f / (1.f + expf(-(iz + biz + bhz)));
        float nn = tanhf(in_ + bin_ + r * bhn);
        float h = (1.f - z) * nn;
        int g = batch[i0 + i];
        if (g != cur_g) {
            atomicAdd(&pooled[(size_t)cur_g * H + t], acc);
            acc = 0.f;
            cur_g = g;
        }
        acc += h;
    }
    atomicAdd(&pooled[(size_t)cur_g * H + t], acc);
}

// --------------------------------------------------------------- super node
__global__ __launch_bounds__(256) void super_kernel(const float* __restrict__ pooled,
                                                    const float* __restrict__ Wf,
                                                    const float* __restrict__ bf,
                                                    float* __restrict__ sup) {
    __shared__ float smean[256];
    int t = threadIdx.x;
    float s = 0.f;
    for (int g = 0; g < G_GRAPHS; g++) s += pooled[(size_t)g * H + t];
    smean[t] = s / (float)G_GRAPHS;
    __syncthreads();
    float acc = 0.f;
    for (int k = 0; k < H; k++) acc += smean[k] * Wf[(size_t)t * H + k];
    acc += bf[t];
    sup[t] = fmaxf(acc, 0.f);
}

__global__ __launch_bounds__(256) void writeout(const float* __restrict__ pooled,
                                                const float* __restrict__ sup,
                                                float* __restrict__ out) {
    int idx = blockIdx.x * 256 + threadIdx.x;   // G*2H = 65536
    int g = idx >> 9, c = idx & 511;
    out[idx] = (c < H) ? pooled[(size_t)g * H + c] : sup[c - H];
}

// ---------------------------------------------------------------- launcher
extern "C" void kernel_launch(void* const* d_in, const int* in_sizes, int n_in,
                              void* d_out, int out_size, void* d_ws, size_t ws_size,
                              hipStream_t stream) {
    const float* x      = (const float*)d_in[0];
    const int*   ei     = (const int*)d_in[1];
    const int*   batch  = (const int*)d_in[2];
    const float* W0     = (const float*)d_in[3];
    const float* a_src0 = (const float*)d_in[4];
    const float* a_dst0 = (const float*)d_in[5];
    const float* b0     = (const float*)d_in[6];
    const float* W1     = (const float*)d_in[7];
    const float* a_src1 = (const float*)d_in[8];
    const float* a_dst1 = (const float*)d_in[9];
    const float* b1     = (const float*)d_in[10];
    const float* W_ih   = (const float*)d_in[11];
    const float* b_ih   = (const float*)d_in[13];
    const float* b_hh   = (const float*)d_in[14];
    const float* Wf     = (const float*)d_in[15];
    const float* bf     = (const float*)d_in[16];
    float* out = (float*)d_out;

    char* p = (char*)d_ws;
    auto alloc = [&](size_t bytes) -> void* {
        void* r = (void*)p;
        p += (bytes + 255) & ~(size_t)255;
        return r;
    };
    u16*   h_bf   = (u16*)alloc((size_t)N_PAD * H * 2);
    u16*   x_bf   = (u16*)alloc((size_t)N_PAD * IN_CH * 2);
    u8*    xp8    = (u8*)alloc((size_t)N_PAD * H);            // own buffer (written during L0 GEMM)
    u16*   gatesC = (u16*)alloc((size_t)N_PAD * 3 * H * 2);   // 77 MB (ws = 256 MB)
    u16*   W0t    = (u16*)alloc((size_t)H * IN_CH * 2);
    u16*   W1t    = (u16*)alloc((size_t)H * H * 2);           // K-permuted
    u16*   Wih_bf = (u16*)alloc((size_t)3 * H * H * 2);       // K-permuted
    float* b0p    = (float*)alloc((size_t)H * 4);
    float* b1p    = (float*)alloc((size_t)H * 4);
    float* s_src  = (float*)alloc((size_t)N_NODES * 4);
    float* s_dst  = (float*)alloc((size_t)N_NODES * 4);
    int2*  rec    = (int2*)alloc((size_t)N_EDGES * 8);
    int*   eidsSrc= (int*)alloc((size_t)ET * 4);
    int*   indptr = (int*)alloc((size_t)(N_NODES + 1) * 4);
    int*   gBkt   = (int*)alloc((size_t)(NB + 1) * 4);
    int*   bktOff = (int*)alloc((size_t)(NB + 1) * 4);
    int*   bktCur = (int*)alloc((size_t)(NB + 1) * 4);
    float* pooled = (float*)alloc((size_t)G_GRAPHS * H * 4);
    float* sup    = (float*)alloc((size_t)H * 4);

    // ---- CSR build (bucketed counting sort) ----
    hipMemsetAsync(gBkt, 0, (size_t)NB * 4, stream);
    bucket_hist<<<NB, 256, 0, stream>>>(ei, gBkt);
    bucket_scan<<<1, 512, 0, stream>>>(gBkt, bktOff, bktCur);
    bucket_scatter<<<(N_EDGES + 256 * EPT - 1) / (256 * EPT), 256, 0, stream>>>(ei, bktCur, rec);
    build_csr<<<NB, 256, 0, stream>>>(rec, bktOff, indptr, eidsSrc);

    // conversions (5 segments)
    prep_kernel<<<dim3((N_NODES * IN_CH / 4 + 255) / 256, 5), 256, 0, stream>>>(
        x, W_ih, W0, W1, b0, b1, x_bf, Wih_bf, W0t, W1t, b0p, b1p);

    const int MB = (N_NODES + 127) / 128;            // 391
    const int WB = N_NODES / 4;                      // 12500
    // GAT layer 0 (fused epilogue: permuted fp8 + s-dots; no bf16 C)
    gemm_wide<true><<<dim3(MB, 1), 256, 0, stream>>>(
        x_bf, W0t, nullptr, xp8, a_src0, a_dst0, s_src, s_dst, N_NODES, IN_CH, H);
    gat_agg_fp8<<<WB, 256, 0, stream>>>(xp8, s_src, s_dst, indptr, eidsSrc, b0p, h_bf);
    // GAT layer 1
    gemm_wide<true><<<dim3(MB, 1), 256, 0, stream>>>(
        h_bf, W1t, nullptr, xp8, a_src1, a_dst1, s_src, s_dst, N_NODES, H, H);
    gat_agg_fp8<<<WB, 256, 0, stream>>>(xp8, s_src, s_dst, indptr, eidsSrc, b1p, h_bf);
    // GRU (single GEMM) + fused pooling
    hipMemsetAsync(pooled, 0, (size_t)G_GRAPHS * H * 4, stream);
    gemm_wide<false><<<dim3(MB, 3), 256, 0, stream>>>(
        h_bf, Wih_bf, gatesC, nullptr, nullptr, nullptr, nullptr, nullptr, N_NODES, H, 3 * H);
    gru_gates_pool<<<(N_NODES + 15) / 16, 256, 0, stream>>>(gatesC, b_ih, b_hh, batch, pooled);
    // super node + writeout
    super_kernel<<<1, 256, 0, stream>>>(pooled, Wf, bf, sup);
    writeout<<<(G_GRAPHS * 2 * H) / 256, 256, 0, stream>>>(pooled, sup, out);
}